// Round 14
// baseline (273.614 us; speedup 1.0000x reference)
//
#include <hip/hip_runtime.h>
#include <hip/hip_bf16.h>
#include <stdint.h>

// Grouped linear: y[z] = coeff * x[z] @ W[idx[z]], idx sorted.
// C=8, U=V=512, Z=32768, fp32 in/out, bf16 MFMA compute.
//
// R14 = R6 schedule with BM=256 (512 thr, 8 waves 4m x 2n, grid 540,
// 3 blocks/CU): halves B fabric traffic (134->66 MB); x panel slice
// (512 KB) L2-resident for the 4 bn-sibling blocks (swizzle-adjacent).
// A: coalesced fp32 reg-stage -> cvt_pk -> ds_write, depth-2 across
// counted-vmcnt raw barriers. B: global_load_lds from pre-tiled bf16 ws.

#define Cg 8
#define Ud 512
#define Vd 512
#define Zd 32768

#define BM 256
#define BN 128
#define BK 32
#define KT 16

#define ATILE_US 8192            // 256 x 32 bf16 = 16 KiB
#define BTILE_US 4096            // 128 x 32 bf16 = 8 KiB
#define NBN 4
#define NBM_MAX 135              // sum ceil(cnt_g/256) <= 128+7
#define GRID_GEMM (NBM_MAX * NBN)    // 540

#define WSW_US (Cg * NBN * KT * BTILE_US)    // 4 MiB of bf16
#define WS_NEEDED ((size_t)WSW_US * 2 + 64)

typedef __attribute__((ext_vector_type(8))) short bf16x8;
typedef __attribute__((ext_vector_type(4))) float f32x4;
typedef __attribute__((ext_vector_type(4))) unsigned short us4;
typedef __attribute__((ext_vector_type(4))) float float4v;
typedef __attribute__((ext_vector_type(4))) unsigned int u32x4;

typedef __attribute__((address_space(3))) unsigned int lds_uint;
typedef const __attribute__((address_space(1))) unsigned int gbl_uint;

__device__ __forceinline__ unsigned int pk2(float lo, float hi) {
    unsigned short l = __bfloat16_as_ushort(__float2bfloat16(lo));
    unsigned short h = __bfloat16_as_ushort(__float2bfloat16(hi));
    return (unsigned int)l | ((unsigned int)h << 16);
}

// Subtile layout within one [R r][32 k] tile (ushort offset):
//   (r>>4)*512 + (k>>3)*128 + (r&15)*8 + (k&7)
// Frag read (lane l): byte = rt*1024 + l4*256 + l15*16 -> contiguous 1 KiB
// per frag across the wave: conflict-free ds_read_b128 (R2/R6-verified).

// ---------------- w converter (+ group starts) ----------------

__global__ __launch_bounds__(256)
void convert_w(const float* __restrict__ w, const int* __restrict__ idx,
               unsigned short* __restrict__ wsw, int* __restrict__ starts)
{
    const int t = blockIdx.x * 256 + threadIdx.x;    // 524288 tasks
    const int g   = t >> 16;
    const int rem = t & 65535;
    const int u0  = (rem >> 9) << 2;                 // 4 k-rows
    const int v   = rem & 511;
    const float* src = w + ((size_t)g << 18) + (size_t)u0 * Vd + v;
    us4 p;
    p[0] = (unsigned short)__bfloat16_as_ushort(__float2bfloat16(src[0]));
    p[1] = (unsigned short)__bfloat16_as_ushort(__float2bfloat16(src[Vd]));
    p[2] = (unsigned short)__bfloat16_as_ushort(__float2bfloat16(src[2 * Vd]));
    p[3] = (unsigned short)__bfloat16_as_ushort(__float2bfloat16(src[3 * Vd]));
    const int r = v & 127, k = u0 & 31;
    const int tile = (g * NBN + (v >> 7)) * KT + (u0 >> 5);
    const int off  = tile * BTILE_US
                   + ((r >> 4) << 9) + ((k >> 3) << 7) + ((r & 15) << 3) + (k & 7);
    *(us4*)(wsw + off) = p;

    if (blockIdx.x == 0 && threadIdx.x < 9) {
        const int gq = threadIdx.x;
        int lo = 0;
        if (gq >= 8) lo = Zd;
        else {
            int hi = Zd;
            while (lo < hi) { int mid = (lo + hi) >> 1;
                              if (idx[mid] < gq) lo = mid + 1; else hi = mid; }
        }
        starts[gq] = lo;
    }
}

// ---------------- GEMM ----------------

#define LDA(KTV, A0, A1, A2, A3) do {                                         \
    const float* p_ = ax + (KTV) * BK;                                        \
    A0 = *(const float4v*)(p_);                                               \
    A1 = *(const float4v*)(p_ + 4);                                           \
    A2 = *(const float4v*)(p_ + 8);                                           \
    A3 = *(const float4v*)(p_ + 12); } while (0)

#define CVW(BUF, A0, A1, A2, A3) do {                                         \
    u32x4 w1_, w2_;                                                           \
    w1_[0] = pk2(A0[0], A0[1]); w1_[1] = pk2(A0[2], A0[3]);                   \
    w1_[2] = pk2(A1[0], A1[1]); w1_[3] = pk2(A1[2], A1[3]);                   \
    w2_[0] = pk2(A2[0], A2[1]); w2_[1] = pk2(A2[2], A2[3]);                   \
    w2_[2] = pk2(A3[0], A3[1]); w2_[3] = pk2(A3[2], A3[3]);                   \
    *(u32x4*)(&BUF[aw])       = w1_;                                          \
    *(u32x4*)(&BUF[aw + 128]) = w2_; } while (0)

#define GLB(KTV, BUF) do {                                                    \
    const unsigned short* s_ = wB + (size_t)(KTV) * BTILE_US;                 \
    __builtin_amdgcn_global_load_lds((gbl_uint*)(s_ + bo),                    \
                                     (lds_uint*)(&BUF[bo]), 16, 0, 0);        \
  } while (0)

#define CMP(ABUF, BBUF) do {                                                  \
    bf16x8 a_[4], b_[4];                                                      \
    _Pragma("unroll")                                                         \
    for (int mi_ = 0; mi_ < 4; ++mi_)                                         \
        a_[mi_] = *(const bf16x8*)(&ABUF[((wm4 + mi_) << 9) + fr]);           \
    _Pragma("unroll")                                                         \
    for (int ni_ = 0; ni_ < 4; ++ni_)                                         \
        b_[ni_] = *(const bf16x8*)(&BBUF[((wn4 + ni_) << 9) + fr]);           \
    _Pragma("unroll")                                                         \
    for (int mi_ = 0; mi_ < 4; ++mi_)                                         \
        _Pragma("unroll")                                                     \
        for (int ni_ = 0; ni_ < 4; ++ni_)                                     \
            acc[mi_][ni_] = __builtin_amdgcn_mfma_f32_16x16x32_bf16(          \
                a_[mi_], b_[ni_], acc[mi_][ni_], 0, 0, 0);                    \
  } while (0)

#define WAITBAR(N) do {                                                       \
    asm volatile("s_waitcnt vmcnt(" #N ") lgkmcnt(0)" ::: "memory");          \
    __builtin_amdgcn_s_barrier(); } while (0)

#define SBAR() __builtin_amdgcn_sched_barrier(0)

__global__ __launch_bounds__(512, 6)
void sgl_gemm(const float* __restrict__ x,
              const unsigned short* __restrict__ wsw,
              const int* __restrict__ starts,
              const float* __restrict__ coeff,
              float* __restrict__ y)
{
    __shared__ unsigned short As[2][ATILE_US];   // 32 KiB
    __shared__ unsigned short Bs[2][BTILE_US];   // 16 KiB -> 48 total

    const int tid = threadIdx.x, lane = tid & 63, wave = tid >> 6;
    const int l15 = lane & 15, l4 = lane >> 4;

    // bijective XCD swizzle (m204): nwg=540, q=67, r=4; consecutive wk share
    // bmp -> the 4 bn-blocks of one x-panel (512 KB slice) on one XCD's L2.
    const int bid = blockIdx.x;
    const int xcd = bid & 7, io = bid >> 3;
    const int wk  = (xcd < 4) ? xcd * 68 + io : 272 + (xcd - 4) * 67 + io;
    const int bmp = wk >> 2, bn = wk & 3;

    // locate group for this padded 256-row block
    int s[9];
#pragma unroll
    for (int i = 0; i < 9; ++i) s[i] = starts[i];
    int g = -1, lblk = 0, ab = 0;
#pragma unroll
    for (int gg = 0; gg < 8; ++gg) {
        const int c  = s[gg + 1] - s[gg];
        const int nb = (c + BM - 1) >> 8;
        if (g < 0 && bmp < ab + nb) { g = gg; lblk = bmp - ab; }
        ab += nb;
    }
    if (g < 0) return;
    const int start = s[g];
    const int cnt   = s[g + 1] - s[g];
    const int j0    = lblk << 8;

    // A: thread t -> row t>>1 (0..255, coalesced pairs), k-half (t&1)*16
    const int ar = tid >> 1;
    const int ak = (tid & 1) << 4;
    const int rc = (j0 + ar < cnt) ? (j0 + ar) : (cnt - 1);
    const float* ax = x + (size_t)(start + rc) * Ud + ak;
    const int aw = ((ar >> 4) << 9) + ((ak >> 3) << 7) + ((ar & 15) << 3);

    // B: linear gload_lds from pre-tiled ws (8 KiB tile, 1 x 16B per thread)
    const unsigned short* wB = wsw + (size_t)((g * NBN + bn) * KT) * BTILE_US;
    const int bo = tid * 8;

    const int wm4 = (wave >> 1) << 2;        // m-tile base: (wave>>1)*64 rows
    const int wn4 = (wave & 1) << 2;         // n-tile base: (wave&1)*64 cols
    const int fr  = (l4 << 7) + (l15 << 3);

    f32x4 acc[4][4];
#pragma unroll
    for (int mi = 0; mi < 4; ++mi)
#pragma unroll
        for (int ni = 0; ni < 4; ++ni)
            acc[mi][ni] = f32x4{0.f, 0.f, 0.f, 0.f};

    float4v e0, e1, e2, e3, o0, o1, o2, o3;

    // prologue: A(0)->e, B(0), A(1)->o ; cvt A(0); barrier leaves A(1) flying
    LDA(0, e0, e1, e2, e3);
    SBAR();
    GLB(0, Bs[0]);
    SBAR();
    LDA(1, o0, o1, o2, o3);
    SBAR();
    CVW(As[0], e0, e1, e2, e3);
    WAITBAR(4);

    // steady: iter kt stages B(kt+1)+A(kt+2), cvts A(kt+1), computes kt.
    // At barrier: B(kt+1) done, A(kt+2) (4 loads) stays in flight -> vmcnt(4).
#pragma unroll
    for (int kt = 0; kt < 14; ++kt) {
        if ((kt & 1) == 0) {
            GLB(kt + 1, Bs[1]);
            SBAR();
            LDA(kt + 2, e0, e1, e2, e3);
            SBAR();
            CVW(As[1], o0, o1, o2, o3);
            CMP(As[0], Bs[0]);
        } else {
            GLB(kt + 1, Bs[0]);
            SBAR();
            LDA(kt + 2, o0, o1, o2, o3);
            SBAR();
            CVW(As[0], e0, e1, e2, e3);
            CMP(As[1], Bs[1]);
        }
        WAITBAR(4);
    }
    // kt = 14 (A(15) is in o; no more prefetch)
    GLB(15, Bs[1]);
    SBAR();
    CVW(As[1], o0, o1, o2, o3);
    CMP(As[0], Bs[0]);
    WAITBAR(0);
    // kt = 15
    CMP(As[1], Bs[1]);

    // epilogue: C/D col=lane&15, row=(lane>>4)*4+q; mask padded rows
    const float cf = coeff[0];
    const bool full = (j0 + BM) <= cnt;
#pragma unroll
    for (int mi = 0; mi < 4; ++mi) {
        const int rb = ((wave >> 1) << 6) + mi * 16 + l4 * 4;
#pragma unroll
        for (int ni = 0; ni < 4; ++ni) {
            const int c = bn * BN + ((wave & 1) << 6) + ni * 16 + l15;
#pragma unroll
            for (int q = 0; q < 4; ++q) {
                if (full || (j0 + rb + q) < cnt)
                    y[(size_t)(start + j0 + rb + q) * Vd + c] = acc[mi][ni][q] * cf;
            }
        }
    }
}

// ---------------- safety-net fallback (ws too small; not expected) --------

__global__ __launch_bounds__(256)
void sgl_naive(const float* __restrict__ w, const float* __restrict__ x,
               const int* __restrict__ idx, const float* __restrict__ coeff,
               float* __restrict__ y)
{
    __shared__ float xs[Ud];
    const int z = blockIdx.x;
    const int g = idx[z];
    for (int u = threadIdx.x; u < Ud; u += 256) xs[u] = x[(size_t)z * Ud + u];
    __syncthreads();
    const float* Wg = w + (size_t)g * (Ud * Vd);
    const float cf = coeff[0];
    for (int v = threadIdx.x; v < Vd; v += 256) {
        float acc = 0.f;
        for (int u = 0; u < Ud; ++u) acc += xs[u] * Wg[(size_t)u * Vd + v];
        y[(size_t)z * Vd + v] = acc * cf;
    }
}

extern "C" void kernel_launch(void* const* d_in, const int* in_sizes, int n_in,
                              void* d_out, int out_size, void* d_ws, size_t ws_size,
                              hipStream_t stream) {
    const float* w     = (const float*)d_in[0];
    const float* x     = (const float*)d_in[1];
    const int*   idx   = (const int*)d_in[2];
    const float* coeff = (const float*)d_in[3];
    float* y = (float*)d_out;

    if (ws_size >= WS_NEEDED) {
        unsigned short* wsw = (unsigned short*)d_ws;
        int* starts = (int*)((char*)d_ws + (size_t)WSW_US * 2);
        hipLaunchKernelGGL(convert_w, dim3(2048), dim3(256), 0, stream,
                           w, idx, wsw, starts);
        hipLaunchKernelGGL(sgl_gemm, dim3(GRID_GEMM), dim3(512), 0, stream,
                           x, wsw, starts, coeff, y);
    } else {
        hipLaunchKernelGGL(sgl_naive, dim3(Zd), dim3(256), 0, stream,
                           w, x, idx, coeff, y);
    }
}

// Round 16
// 55.280 us; speedup vs baseline: 4.9496x; 4.9496x over previous
//
#include <hip/hip_runtime.h>
#include <hip/hip_bf16.h>
#include <stdint.h>

// Grouped linear: y[z] = coeff * x[z] @ W[idx[z]], idx sorted.
// C=8, U=V=512, Z=32768, fp32 in/out, bf16 MFMA compute.
//
// R16 = R11's proven 256-thread counted-vmcnt pipeline at BK=64 cadence
// (R2's best-measured GEMM cadence): 8 barrier periods instead of 16.
// Per period: stage B super-tile (4 gload_lds), prefetch A super-tile T+2
// (8 fp32 loads), cvt+ds_write A super-tile T+1, compute T (32 MFMA).
// WAITBAR(8): drains B, leaves the 8 A-loads in flight. 256 threads,
// launch_bounds(256,2) -> VGPR cap 256 (~165 used, NO spill -> vmcnt
// contract safe; R15's race was spill ops corrupting the count).

#define Cg 8
#define Ud 512
#define Vd 512
#define Zd 32768

#define BM 128
#define BN 128
#define KT 16                    // 32-k tiles; 8 super-tiles of 64

#define TILE_US 4096             // 128 x 32 bf16 = 8 KiB
#define NBN 4
#define NBM_MAX 263              // sum ceil(cnt_g/128) <= 256+7
#define GRID_GEMM (NBM_MAX * NBN)    // 1052

#define WSW_US (Cg * NBN * KT * TILE_US)     // 4 MiB of bf16
#define WS_NEEDED ((size_t)WSW_US * 2 + 64)

typedef __attribute__((ext_vector_type(8))) short bf16x8;
typedef __attribute__((ext_vector_type(4))) float f32x4;
typedef __attribute__((ext_vector_type(4))) unsigned short us4;
typedef __attribute__((ext_vector_type(4))) float float4v;
typedef __attribute__((ext_vector_type(4))) unsigned int u32x4;

typedef __attribute__((address_space(3))) unsigned int lds_uint;
typedef const __attribute__((address_space(1))) unsigned int gbl_uint;

__device__ __forceinline__ unsigned int pk2(float lo, float hi) {
    unsigned short l = __bfloat16_as_ushort(__float2bfloat16(lo));
    unsigned short h = __bfloat16_as_ushort(__float2bfloat16(hi));
    return (unsigned int)l | ((unsigned int)h << 16);
}

// Subtile layout within one [128 r][32 k] tile (ushort offset):
//   (r>>4)*512 + (k>>3)*128 + (r&15)*8 + (k&7)
// Frag read (lane l): byte = rt*1024 + l4*256 + l15*16 -> contiguous 1 KiB
// per frag across the wave: conflict-free ds_read_b128 (R2/R6-verified).

// ---------------- w converter (+ group starts) ----------------

__global__ __launch_bounds__(256)
void convert_w(const float* __restrict__ w, const int* __restrict__ idx,
               unsigned short* __restrict__ wsw, int* __restrict__ starts)
{
    const int t = blockIdx.x * 256 + threadIdx.x;    // 524288 tasks
    const int g   = t >> 16;
    const int rem = t & 65535;
    const int u0  = (rem >> 9) << 2;                 // 4 k-rows
    const int v   = rem & 511;
    const float* src = w + ((size_t)g << 18) + (size_t)u0 * Vd + v;
    us4 p;
    p[0] = (unsigned short)__bfloat16_as_ushort(__float2bfloat16(src[0]));
    p[1] = (unsigned short)__bfloat16_as_ushort(__float2bfloat16(src[Vd]));
    p[2] = (unsigned short)__bfloat16_as_ushort(__float2bfloat16(src[2 * Vd]));
    p[3] = (unsigned short)__bfloat16_as_ushort(__float2bfloat16(src[3 * Vd]));
    const int r = v & 127, k = u0 & 31;
    const int tile = (g * NBN + (v >> 7)) * KT + (u0 >> 5);
    const int off  = tile * TILE_US
                   + ((r >> 4) << 9) + ((k >> 3) << 7) + ((r & 15) << 3) + (k & 7);
    *(us4*)(wsw + off) = p;

    if (blockIdx.x == 0 && threadIdx.x < 9) {
        const int gq = threadIdx.x;
        int lo = 0;
        if (gq >= 8) lo = Zd;
        else {
            int hi = Zd;
            while (lo < hi) { int mid = (lo + hi) >> 1;
                              if (idx[mid] < gq) lo = mid + 1; else hi = mid; }
        }
        starts[gq] = lo;
    }
}

// ---------------- GEMM ----------------

#define LDA32(KTV, Q0, Q1, Q2, Q3) do {                                       \
    const float* p_ = ax + (KTV) * 32;                                        \
    Q0 = *(const float4v*)(p_);                                               \
    Q1 = *(const float4v*)(p_ + 4);                                           \
    Q2 = *(const float4v*)(p_ + 8);                                           \
    Q3 = *(const float4v*)(p_ + 12); } while (0)

#define CVW32(PTR, Q0, Q1, Q2, Q3) do {                                       \
    u32x4 w1_, w2_;                                                           \
    w1_[0] = pk2(Q0[0], Q0[1]); w1_[1] = pk2(Q0[2], Q0[3]);                   \
    w1_[2] = pk2(Q1[0], Q1[1]); w1_[3] = pk2(Q1[2], Q1[3]);                   \
    w2_[0] = pk2(Q2[0], Q2[1]); w2_[1] = pk2(Q2[2], Q2[3]);                   \
    w2_[2] = pk2(Q3[0], Q3[1]); w2_[3] = pk2(Q3[2], Q3[3]);                   \
    *(u32x4*)((PTR) + aw)       = w1_;                                        \
    *(u32x4*)((PTR) + aw + 128) = w2_; } while (0)

#define GLB32(KTV, PTR) do {                                                  \
    const unsigned short* s_ = wB + (size_t)(KTV) * TILE_US;                  \
    __builtin_amdgcn_global_load_lds((gbl_uint*)(s_ + bo),                    \
                                     (lds_uint*)((PTR) + bo), 16, 0, 0);      \
    __builtin_amdgcn_global_load_lds((gbl_uint*)(s_ + bo + 2048),             \
                                     (lds_uint*)((PTR) + bo + 2048), 16, 0, 0); \
  } while (0)

#define CMP32(AP, BP) do {                                                    \
    bf16x8 a_[4], b_[4];                                                      \
    _Pragma("unroll")                                                         \
    for (int mi_ = 0; mi_ < 4; ++mi_)                                         \
        a_[mi_] = *(const bf16x8*)((AP) + ((wm4 + mi_) << 9) + fr);           \
    _Pragma("unroll")                                                         \
    for (int ni_ = 0; ni_ < 4; ++ni_)                                         \
        b_[ni_] = *(const bf16x8*)((BP) + ((wn4 + ni_) << 9) + fr);           \
    _Pragma("unroll")                                                         \
    for (int mi_ = 0; mi_ < 4; ++mi_)                                         \
        _Pragma("unroll")                                                     \
        for (int ni_ = 0; ni_ < 4; ++ni_)                                     \
            acc[mi_][ni_] = __builtin_amdgcn_mfma_f32_16x16x32_bf16(          \
                a_[mi_], b_[ni_], acc[mi_][ni_], 0, 0, 0);                    \
  } while (0)

#define WAITBAR(N) do {                                                       \
    asm volatile("s_waitcnt vmcnt(" #N ") lgkmcnt(0)" ::: "memory");          \
    __builtin_amdgcn_s_barrier(); } while (0)

#define SBAR() __builtin_amdgcn_sched_barrier(0)

__global__ __launch_bounds__(256, 2)
void sgl_gemm(const float* __restrict__ x,
              const unsigned short* __restrict__ wsw,
              const int* __restrict__ starts,
              const float* __restrict__ coeff,
              float* __restrict__ y)
{
    __shared__ unsigned short As[2][2 * TILE_US];    // 32 KiB (2 halves each)
    __shared__ unsigned short Bs[2][2 * TILE_US];    // 32 KiB -> 64 total

    const int tid = threadIdx.x, lane = tid & 63, wave = tid >> 6;
    const int l15 = lane & 15, l4 = lane >> 4;

    // bijective XCD swizzle (m204): nwg=1052, q=131, r=4; consecutive wk
    // share bmp -> the 4 bn-blocks of one x-panel land on one XCD (L2 reuse).
    const int bid = blockIdx.x;
    const int xcd = bid & 7, io = bid >> 3;
    const int wk  = (xcd < 4) ? xcd * 132 + io : 528 + (xcd - 4) * 131 + io;
    const int bmp = wk >> 2, bn = wk & 3;

    // locate group for this padded row-block
    int s[9];
#pragma unroll
    for (int i = 0; i < 9; ++i) s[i] = starts[i];
    int g = -1, lblk = 0, ab = 0;
#pragma unroll
    for (int gg = 0; gg < 8; ++gg) {
        const int c  = s[gg + 1] - s[gg];
        const int nb = (c + BM - 1) >> 7;
        if (g < 0 && bmp < ab + nb) { g = gg; lblk = bmp - ab; }
        ab += nb;
    }
    if (g < 0) return;
    const int start = s[g];
    const int cnt   = s[g + 1] - s[g];
    const int j0    = lblk << 7;

    // A: thread t -> row t>>1 (coalesced pairs), k-half (t&1)*16; clamp pads
    const int ar = tid >> 1;
    const int ak = (tid & 1) << 4;
    const int rc = (j0 + ar < cnt) ? (j0 + ar) : (cnt - 1);
    const float* ax = x + (size_t)(start + rc) * Ud + ak;
    const int aw = ((ar >> 4) << 9) + ((ak >> 3) << 7) + ((ar & 15) << 3);

    // B: linear gload_lds from pre-tiled ws
    const unsigned short* wB = wsw + (size_t)((g * NBN + bn) * KT) * TILE_US;
    const int bo = tid * 8;

    const int wm4 = (wave >> 1) << 2;
    const int wn4 = (wave & 1) << 2;
    const int fr  = (l4 << 7) + (l15 << 3);

    f32x4 acc[4][4];
#pragma unroll
    for (int mi = 0; mi < 4; ++mi)
#pragma unroll
        for (int ni = 0; ni < 4; ++ni)
            acc[mi][ni] = f32x4{0.f, 0.f, 0.f, 0.f};

    // super-tile T (k = 64T..64T+63) = 32-k tiles {2T, 2T+1}.
    // Set e holds even-T raw A, set o odd-T. Sequence per period:
    //   GLB(B of T+1) -> LDA(A of T+2) -> CVW(A of T+1) -> CMP(T) -> WAITBAR(8)
    // Outstanding at barrier: 4 (B of T+1: wait) + 8 (A of T+2: keep flying).
    float4v e0, e1, e2, e3, e4, e5, e6, e7;
    float4v o0, o1, o2, o3, o4, o5, o6, o7;

    // prologue: B(ST0), A(ST0)->e, A(ST1)->o; cvt ST0
    GLB32(0, &Bs[0][0]);
    GLB32(1, &Bs[0][TILE_US]);
    SBAR();
    LDA32(0, e0, e1, e2, e3);
    LDA32(1, e4, e5, e6, e7);
    SBAR();
    LDA32(2, o0, o1, o2, o3);
    LDA32(3, o4, o5, o6, o7);
    SBAR();
    CVW32(&As[0][0],       e0, e1, e2, e3);   // waits A(ST0); drains B(ST0)
    CVW32(&As[0][TILE_US], e4, e5, e6, e7);
    WAITBAR(8);                               // vmcnt no-op (ST1 A flying)

#pragma unroll
    for (int T = 0; T < 6; ++T) {
        if ((T & 1) == 0) {
            GLB32(2 * T + 2, &Bs[1][0]);
            GLB32(2 * T + 3, &Bs[1][TILE_US]);
            SBAR();
            LDA32(2 * T + 4, e0, e1, e2, e3);     // ST T+2 -> set e
            LDA32(2 * T + 5, e4, e5, e6, e7);
            SBAR();
            CVW32(&As[1][0],       o0, o1, o2, o3);   // ST T+1 (set o)
            CVW32(&As[1][TILE_US], o4, o5, o6, o7);
            CMP32(&As[0][0],       &Bs[0][0]);        // ST T
            CMP32(&As[0][TILE_US], &Bs[0][TILE_US]);
        } else {
            GLB32(2 * T + 2, &Bs[0][0]);
            GLB32(2 * T + 3, &Bs[0][TILE_US]);
            SBAR();
            LDA32(2 * T + 4, o0, o1, o2, o3);     // ST T+2 -> set o
            LDA32(2 * T + 5, o4, o5, o6, o7);
            SBAR();
            CVW32(&As[0][0],       e0, e1, e2, e3);   // ST T+1 (set e)
            CVW32(&As[0][TILE_US], e4, e5, e6, e7);
            CMP32(&As[1][0],       &Bs[1][0]);        // ST T
            CMP32(&As[1][TILE_US], &Bs[1][TILE_US]);
        }
        WAITBAR(8);
    }
    // T = 6 (even): B(ST7); cvt ST7 (set o, loaded at T=5); compute ST6
    GLB32(14, &Bs[1][0]);
    GLB32(15, &Bs[1][TILE_US]);
    SBAR();
    CVW32(&As[1][0],       o0, o1, o2, o3);
    CVW32(&As[1][TILE_US], o4, o5, o6, o7);
    CMP32(&As[0][0],       &Bs[0][0]);
    CMP32(&As[0][TILE_US], &Bs[0][TILE_US]);
    WAITBAR(0);                               // drain B(ST7)
    // T = 7
    CMP32(&As[1][0],       &Bs[1][0]);
    CMP32(&As[1][TILE_US], &Bs[1][TILE_US]);

    // epilogue: C/D col=lane&15, row=(lane>>4)*4+q; mask padded rows
    const float cf = coeff[0];
    const bool full = (j0 + BM) <= cnt;
#pragma unroll
    for (int mi = 0; mi < 4; ++mi) {
        const int rb = ((wave >> 1) << 6) + mi * 16 + l4 * 4;
#pragma unroll
        for (int ni = 0; ni < 4; ++ni) {
            const int c = bn * BN + ((wave & 1) << 6) + ni * 16 + l15;
#pragma unroll
            for (int q = 0; q < 4; ++q) {
                if (full || (j0 + rb + q) < cnt)
                    y[(size_t)(start + j0 + rb + q) * Vd + c] = acc[mi][ni][q] * cf;
            }
        }
    }
}

// ---------------- safety-net fallback (ws too small; not expected) --------

__global__ __launch_bounds__(256)
void sgl_naive(const float* __restrict__ w, const float* __restrict__ x,
               const int* __restrict__ idx, const float* __restrict__ coeff,
               float* __restrict__ y)
{
    __shared__ float xs[Ud];
    const int z = blockIdx.x;
    const int g = idx[z];
    for (int u = threadIdx.x; u < Ud; u += 256) xs[u] = x[(size_t)z * Ud + u];
    __syncthreads();
    const float* Wg = w + (size_t)g * (Ud * Vd);
    const float cf = coeff[0];
    for (int v = threadIdx.x; v < Vd; v += 256) {
        float acc = 0.f;
        for (int u = 0; u < Ud; ++u) acc += xs[u] * Wg[(size_t)u * Vd + v];
        y[(size_t)z * Vd + v] = acc * cf;
    }
}

extern "C" void kernel_launch(void* const* d_in, const int* in_sizes, int n_in,
                              void* d_out, int out_size, void* d_ws, size_t ws_size,
                              hipStream_t stream) {
    const float* w     = (const float*)d_in[0];
    const float* x     = (const float*)d_in[1];
    const int*   idx   = (const int*)d_in[2];
    const float* coeff = (const float*)d_in[3];
    float* y = (float*)d_out;

    if (ws_size >= WS_NEEDED) {
        unsigned short* wsw = (unsigned short*)d_ws;
        int* starts = (int*)((char*)d_ws + (size_t)WSW_US * 2);
        hipLaunchKernelGGL(convert_w, dim3(2048), dim3(256), 0, stream,
                           w, idx, wsw, starts);
        hipLaunchKernelGGL(sgl_gemm, dim3(GRID_GEMM), dim3(256), 0, stream,
                           x, wsw, starts, coeff, y);
    } else {
        hipLaunchKernelGGL(sgl_naive, dim3(Zd), dim3(256), 0, stream,
                           w, x, idx, coeff, y);
    }
}